// Round 3
// baseline (235.936 us; speedup 1.0000x reference)
//
#include <hip/hip_runtime.h>
#include <hip/hip_fp16.h>
#include <cstdint>
#include <cstddef>

// VideoSAGE: prep(weights) -> proj GEMM (fused fp32->fp16 cvt of x in A-staging)
// -> 3x GCN GEMM (fused tridiag band mix in A-staging, via adj@(hW)=(adj h)W)
// -> fused head. fp16 MFMA 16x16x32, fp32 accum.

typedef _Float16 f16;
typedef _Float16 f16x8 __attribute__((ext_vector_type(8)));
typedef float    f32x4 __attribute__((ext_vector_type(4)));

__device__ __forceinline__ void async_cp16(const void* g, void* l) {
  __builtin_amdgcn_global_load_lds((const __attribute__((address_space(1))) void*)g,
                                   (__attribute__((address_space(3))) void*)l, 16, 0, 0);
}

__device__ __forceinline__ f16x8 splat8(f16 v) {
  f16x8 r;
#pragma unroll
  for (int e = 0; e < 8; ++e) r[e] = v;
  return r;
}

// ---------------------------------------------------------------------------
// GEMM: C[M,N] = act(A' * BT[N,K]^T + bias)
// AMODE: 1 = A is fp32 [M,K], convert to fp16 during staging (proj)
//        2 = A is fp16 [M,K], band-mix rows (adj tridiag) during staging (GCN)
// B always staged with global_load_lds width=16. XOR chunk swizzle applied on
// the source chunk index so LDS stays lane-linear (m104 caveat) and read-side
// banks stay conflict-free.
// ---------------------------------------------------------------------------
template<int BM, int BN, int WAVES_M, int WAVES_N, bool RELU, bool HAS_BIAS, int AMODE>
__global__ __launch_bounds__(256) void gemm_f16_kernel(
    const void* __restrict__ Aptr, const f16* __restrict__ BT,
    f16* __restrict__ C, const float* __restrict__ bias,
    int M, int N, int K)
{
  constexpr int BK = 64;
  constexpr int WM = BM / WAVES_M;
  constexpr int WN = BN / WAVES_N;
  constexpr int TM = WM / 16;
  constexpr int TN = WN / 16;
  constexpr int ITER_A = (BM * BK) / (256 * 8);
  constexpr int ITER_B = (BN * BK) / (256 * 8);
  constexpr int S = 2048;

  __shared__ __align__(16) f16 sA[BM * BK];
  __shared__ __align__(16) f16 sB[BN * BK];

  const int tid  = threadIdx.x;
  const int lane = tid & 63;
  const int wave = tid >> 6;
  const int wm   = wave / WAVES_N;
  const int wn   = wave % WAVES_N;
  const int m0   = blockIdx.x * BM;
  const int n0   = blockIdx.y * BN;

  // ---- hoisted per-chunk staging state (rows/coeffs fixed across kt) ----
  uint32_t offA[ITER_A][3];   // byte offsets (mode 2: prev/self/next)
  f16      cfA[ITER_A][3];    // band coefficients (mode 2)
  const float dM = 0.57735026919f;   // (3+1e-8)^-1/2
  const float dE = 0.70710678118f;   // (2+1e-8)^-1/2
#pragma unroll
  for (int j = 0; j < ITER_A; ++j) {
    const int linear = j * 256 + tid;
    const int row = linear >> 3;
    const int q   = (linear & 7) ^ (row & 7);
    const int gm  = m0 + row;
    if constexpr (AMODE == 1) {
      offA[j][0] = (uint32_t)(((size_t)gm * K + q * 8) * 4);
    } else {
      const int s = gm & (S - 1);
      const float dsv = (s == 0 || s == S - 1) ? dE : dM;
      const float cpf = (s > 0)     ? dsv * ((s - 1 == 0) ? dE : dM)     : 0.0f;
      const float csf = dsv * dsv;
      const float cnf = (s < S - 1) ? dsv * ((s + 1 == S - 1) ? dE : dM) : 0.0f;
      const int rm1 = (s > 0)     ? gm - 1 : gm;
      const int rp1 = (s < S - 1) ? gm + 1 : gm;
      offA[j][0] = (uint32_t)(((size_t)rm1 * K + q * 8) * 2);
      offA[j][1] = (uint32_t)(((size_t)gm  * K + q * 8) * 2);
      offA[j][2] = (uint32_t)(((size_t)rp1 * K + q * 8) * 2);
      cfA[j][0] = (f16)cpf; cfA[j][1] = (f16)csf; cfA[j][2] = (f16)cnf;
    }
  }

  f32x4 acc[TM][TN];
#pragma unroll
  for (int i = 0; i < TM; ++i)
#pragma unroll
    for (int j = 0; j < TN; ++j)
      acc[i][j] = (f32x4){0.f, 0.f, 0.f, 0.f};

  const int quad = lane >> 4;
  const int l16  = lane & 15;

  for (int kt = 0; kt < K; kt += BK) {
    __syncthreads();
    // ---- A staging (VGPR-mediated, fused transform) ----
    if constexpr (AMODE == 1) {
      const char* base = (const char*)Aptr + (size_t)kt * 4;
#pragma unroll
      for (int j = 0; j < ITER_A; ++j) {
        const float4* p = (const float4*)(base + offA[j][0]);
        const float4 a = p[0], b = p[1];
        f16x8 o;
        o[0] = (f16)a.x;  o[1] = (f16)a.y;  o[2] = (f16)a.z;  o[3] = (f16)a.w;
        o[4] = (f16)b.x;  o[5] = (f16)b.y;  o[6] = (f16)b.z;  o[7] = (f16)b.w;
        *(f16x8*)&sA[(size_t)(j * 256 + tid) * 8] = o;
      }
    } else {
      const char* base = (const char*)Aptr + (size_t)kt * 2;
#pragma unroll
      for (int j = 0; j < ITER_A; ++j) {
        f16x8 pv = *(const f16x8*)(base + offA[j][0]);
        f16x8 sv = *(const f16x8*)(base + offA[j][1]);
        f16x8 nv = *(const f16x8*)(base + offA[j][2]);
        f16x8 r = pv * splat8(cfA[j][0]);
        r += sv * splat8(cfA[j][1]);
        r += nv * splat8(cfA[j][2]);
        *(f16x8*)&sA[(size_t)(j * 256 + tid) * 8] = r;
      }
    }
    // ---- B staging (async direct-to-LDS) ----
#pragma unroll
    for (int j = 0; j < ITER_B; ++j) {
      const int linear = j * 256 + tid;
      const int row = linear >> 3;
      const int q   = (linear & 7) ^ (row & 7);
      async_cp16(BT + (size_t)(n0 + row) * K + kt + q * 8, &sB[linear * 8]);
    }
    __syncthreads();

#pragma unroll
    for (int kk = 0; kk < 2; ++kk) {
      const int c = quad + kk * 4;
      f16x8 af[TM], bf[TN];
#pragma unroll
      for (int mi = 0; mi < TM; ++mi) {
        const int ml = wm * WM + mi * 16 + l16;
        af[mi] = *(const f16x8*)&sA[ml * 64 + ((c ^ (ml & 7)) * 8)];
      }
#pragma unroll
      for (int ni = 0; ni < TN; ++ni) {
        const int nl = wn * WN + ni * 16 + l16;
        bf[ni] = *(const f16x8*)&sB[nl * 64 + ((c ^ (nl & 7)) * 8)];
      }
#pragma unroll
      for (int mi = 0; mi < TM; ++mi)
#pragma unroll
        for (int ni = 0; ni < TN; ++ni)
          acc[mi][ni] = __builtin_amdgcn_mfma_f32_16x16x32_f16(
              af[mi], bf[ni], acc[mi][ni], 0, 0, 0);
    }
  }

  // C/D layout: col = lane&15, row = quad*4 + reg (m89/m91-verified).
#pragma unroll
  for (int ni = 0; ni < TN; ++ni) {
    const int nc = n0 + wn * WN + ni * 16 + l16;
    const float bv = HAS_BIAS ? bias[nc] : 0.0f;
#pragma unroll
    for (int mi = 0; mi < TM; ++mi) {
#pragma unroll
      for (int r = 0; r < 4; ++r) {
        const int mr = m0 + wm * WM + mi * 16 + quad * 4 + r;
        float v = acc[mi][ni][r] + bv;
        if (RELU) v = fmaxf(v, 0.0f);
        C[(size_t)mr * N + nc] = (f16)v;
      }
    }
  }
}

// ---------------------------------------------------------------------------
// Fused head: per 64-row block, z1 in LDS -> z2 in LDS -> sigmoid dot.
// ---------------------------------------------------------------------------
__global__ __launch_bounds__(256) void head_fused_kernel(
    const f16* __restrict__ h, const f16* __restrict__ S1T,
    const f16* __restrict__ S2T,
    const float* __restrict__ s1b, const float* __restrict__ s2b,
    const float* __restrict__ s3w, const float* __restrict__ s3b,
    float* __restrict__ out)
{
  __shared__ __align__(16) char smem[40960 + 64 * 264 * 2];
  f16* sA  = (f16*)smem;             // [64*64]
  f16* sB  = (f16*)(smem + 8192);    // [256*64]
  f16* zs  = (f16*)(smem + 40960);   // [64][264]
  f16* z2s = (f16*)smem;             // [64][136] (reuses sA)
  f16* sB2 = (f16*)(smem + 17408);   // [128*64]  (reuses sB)

  const int tid  = threadIdx.x;
  const int lane = tid & 63;
  const int wave = tid >> 6;
  const int quad = lane >> 4;
  const int l16  = lane & 15;
  const int m0   = blockIdx.x * 64;

  f32x4 acc[4][4];
#pragma unroll
  for (int i = 0; i < 4; ++i)
#pragma unroll
    for (int j = 0; j < 4; ++j) acc[i][j] = (f32x4){0.f, 0.f, 0.f, 0.f};

  for (int kt = 0; kt < 512; kt += 64) {
    __syncthreads();
#pragma unroll
    for (int j = 0; j < 2; ++j) {
      const int linear = j * 256 + tid;
      const int row = linear >> 3;
      const int q   = (linear & 7) ^ (row & 7);
      async_cp16(h + (size_t)(m0 + row) * 512 + kt + q * 8, &sA[linear * 8]);
    }
#pragma unroll
    for (int j = 0; j < 8; ++j) {
      const int linear = j * 256 + tid;
      const int row = linear >> 3;
      const int q   = (linear & 7) ^ (row & 7);
      async_cp16(S1T + (size_t)row * 512 + kt + q * 8, &sB[linear * 8]);
    }
    __syncthreads();
#pragma unroll
    for (int kk = 0; kk < 2; ++kk) {
      const int c = quad + kk * 4;
      f16x8 af[4], bf[4];
#pragma unroll
      for (int mi = 0; mi < 4; ++mi) {
        const int ml = mi * 16 + l16;
        af[mi] = *(const f16x8*)&sA[ml * 64 + ((c ^ (ml & 7)) * 8)];
      }
#pragma unroll
      for (int ni = 0; ni < 4; ++ni) {
        const int nl = wave * 64 + ni * 16 + l16;
        bf[ni] = *(const f16x8*)&sB[nl * 64 + ((c ^ (nl & 7)) * 8)];
      }
#pragma unroll
      for (int mi = 0; mi < 4; ++mi)
#pragma unroll
        for (int ni = 0; ni < 4; ++ni)
          acc[mi][ni] = __builtin_amdgcn_mfma_f32_16x16x32_f16(
              af[mi], bf[ni], acc[mi][ni], 0, 0, 0);
    }
  }
#pragma unroll
  for (int ni = 0; ni < 4; ++ni) {
    const int nc = wave * 64 + ni * 16 + l16;
    const float bv = s1b[nc];
#pragma unroll
    for (int mi = 0; mi < 4; ++mi)
#pragma unroll
      for (int r = 0; r < 4; ++r) {
        const int row = mi * 16 + quad * 4 + r;
        zs[row * 264 + nc] = (f16)fmaxf(acc[mi][ni][r] + bv, 0.0f);
      }
  }
  __syncthreads();

  f32x4 acc2[4][2];
#pragma unroll
  for (int i = 0; i < 4; ++i)
#pragma unroll
    for (int j = 0; j < 2; ++j) acc2[i][j] = (f32x4){0.f, 0.f, 0.f, 0.f};

  for (int kt2 = 0; kt2 < 4; ++kt2) {
    __syncthreads();
#pragma unroll
    for (int j = 0; j < 4; ++j) {
      const int linear = j * 256 + tid;
      const int row = linear >> 3;
      const int q   = (linear & 7) ^ (row & 7);
      async_cp16(S2T + (size_t)row * 256 + kt2 * 64 + q * 8, &sB2[linear * 8]);
    }
    __syncthreads();
#pragma unroll
    for (int kk = 0; kk < 2; ++kk) {
      const int c = quad + kk * 4;
      f16x8 af[4], bf[2];
#pragma unroll
      for (int mi = 0; mi < 4; ++mi) {
        const int row = mi * 16 + l16;
        af[mi] = *(const f16x8*)&zs[row * 264 + (kt2 * 8 + c) * 8];
      }
#pragma unroll
      for (int ni = 0; ni < 2; ++ni) {
        const int nl = wave * 32 + ni * 16 + l16;
        bf[ni] = *(const f16x8*)&sB2[nl * 64 + ((c ^ (nl & 7)) * 8)];
      }
#pragma unroll
      for (int mi = 0; mi < 4; ++mi)
#pragma unroll
        for (int ni = 0; ni < 2; ++ni)
          acc2[mi][ni] = __builtin_amdgcn_mfma_f32_16x16x32_f16(
              af[mi], bf[ni], acc2[mi][ni], 0, 0, 0);
    }
  }
  __syncthreads();
#pragma unroll
  for (int ni = 0; ni < 2; ++ni) {
    const int nc = wave * 32 + ni * 16 + l16;
    const float bv = s2b[nc];
#pragma unroll
    for (int mi = 0; mi < 4; ++mi)
#pragma unroll
      for (int r = 0; r < 4; ++r) {
        const int row = mi * 16 + quad * 4 + r;
        z2s[row * 136 + nc] = (f16)fmaxf(acc2[mi][ni][r] + bv, 0.0f);
      }
  }
  __syncthreads();

  const int m = tid >> 2;
  const int qd = tid & 3;
  float p = 0.f;
#pragma unroll
  for (int j = 0; j < 4; ++j) {
    f16x8 v = *(const f16x8*)&z2s[m * 136 + qd * 32 + j * 8];
#pragma unroll
    for (int e = 0; e < 8; ++e) p += (float)v[e] * s3w[qd * 32 + j * 8 + e];
  }
  p += __shfl_xor(p, 1);
  p += __shfl_xor(p, 2);
  if (qd == 0) out[m0 + m] = 1.0f / (1.0f + expf(-(p + s3b[0])));
}

// ---------------------------------------------------------------------------
// Prep: 64x64 LDS tile-transposes of all weights (coalesced both sides).
// ---------------------------------------------------------------------------
__global__ __launch_bounds__(256) void prep_kernel(
    const float* __restrict__ Wp, f16* __restrict__ WpT,
    const float* __restrict__ gW, f16* __restrict__ GT,
    const float* __restrict__ s1W, f16* __restrict__ S1T,
    const float* __restrict__ s2W, f16* __restrict__ S2T)
{
  __shared__ f16 s[64 * 68];
  const int tid = threadIdx.x;
  int b = blockIdx.x;

  const float* W; f16* WT; int K, N, tile;
  if (b < 128)      { W = Wp;  WT = WpT; K = 1024; N = 512; tile = b; }
  else if (b < 320) { const int i = (b - 128) >> 6;
                      W = gW + (size_t)i * 262144; WT = GT + (size_t)i * 262144;
                      K = 512; N = 512; tile = (b - 128) & 63; }
  else if (b < 352) { W = s1W; WT = S1T; K = 512; N = 256; tile = b - 320; }
  else              { W = s2W; WT = S2T; K = 256; N = 128; tile = b - 352; }

  const int nt = tile % (N >> 6);
  const int kt = tile / (N >> 6);
#pragma unroll
  for (int it = 0; it < 16; ++it) {
    const int i  = it * 256 + tid;
    const int rk = i >> 6, rn = i & 63;
    s[rn * 68 + rk] = (f16)W[(size_t)(kt * 64 + rk) * N + nt * 64 + rn];
  }
  __syncthreads();
#pragma unroll
  for (int it = 0; it < 16; ++it) {
    const int i  = it * 256 + tid;
    const int rn = i >> 6, rk = i & 63;
    WT[(size_t)(nt * 64 + rn) * K + kt * 64 + rk] = s[rn * 68 + rk];
  }
}

// ---------------------------------------------------------------------------
extern "C" void kernel_launch(void* const* d_in, const int* in_sizes, int n_in,
                              void* d_out, int out_size, void* d_ws, size_t ws_size,
                              hipStream_t stream) {
  (void)in_sizes; (void)n_in; (void)out_size; (void)ws_size;
  const float* x   = (const float*)d_in[0];
  const float* Wp  = (const float*)d_in[1];
  const float* bp  = (const float*)d_in[2];
  const float* gW  = (const float*)d_in[3];
  const float* gb  = (const float*)d_in[4];
  const float* s1W = (const float*)d_in[5];
  const float* s1b = (const float*)d_in[6];
  const float* s2W = (const float*)d_in[7];
  const float* s2b = (const float*)d_in[8];
  const float* s3W = (const float*)d_in[9];
  const float* s3b = (const float*)d_in[10];
  float* out = (float*)d_out;

  constexpr int M = 16384;
  char* ws = (char*)d_ws;
  f16* hA  = (f16*)(ws + 0);            // 16384x512
  f16* hB  = (f16*)(ws + 16777216);     // 16384x512
  f16* WpT = (f16*)(ws + 33554432);     // [512,1024]
  f16* GT  = (f16*)(ws + 34603008);     // 3x[512,512]
  f16* S1T = (f16*)(ws + 36175872);     // [256,512]
  f16* S2T = (f16*)(ws + 36438016);     // [128,256]

  prep_kernel<<<360, 256, 0, stream>>>(Wp, WpT, gW, GT, s1W, S1T, s2W, S2T);

  // proj: hA = x @ Wp + bp  (x converted fp32->fp16 during A-staging)
  gemm_f16_kernel<128, 128, 2, 2, false, true, 1>
      <<<dim3(M / 128, 4), 256, 0, stream>>>(x, WpT, hA, bp, M, 512, 1024);

  // GCN layers: h' = (adj @ h) @ W + b  (band mix fused into A-staging)
  gemm_f16_kernel<128, 128, 2, 2, true, true, 2>
      <<<dim3(M / 128, 4), 256, 0, stream>>>(hA, GT, hB, gb, M, 512, 512);
  gemm_f16_kernel<128, 128, 2, 2, true, true, 2>
      <<<dim3(M / 128, 4), 256, 0, stream>>>(hB, GT + 262144, hA, gb + 512, M, 512, 512);
  gemm_f16_kernel<128, 128, 2, 2, false, true, 2>
      <<<dim3(M / 128, 4), 256, 0, stream>>>(hA, GT + 524288, hB, gb + 1024, M, 512, 512);

  head_fused_kernel<<<M / 64, 256, 0, stream>>>(hB, S1T, S2T, s1b, s2b, s3W, s3b, out);
}

// Round 4
// 209.160 us; speedup vs baseline: 1.1280x; 1.1280x over previous
//
#include <hip/hip_runtime.h>
#include <hip/hip_fp16.h>
#include <cstdint>
#include <cstddef>

// VideoSAGE: prep(weights) -> proj GEMM (fused fp32->fp16 cvt of x in A-staging)
// -> 3x GCN GEMM (fused tridiag band mix in A-staging, via adj@(hW)=(adj h)W)
// -> fused head. fp16 MFMA 16x16x32, fp32 accum.
// R4: BM 128->64 (grid 512->1024, ~5 blocks/CU) to fix 15% occupancy;
//     head BM 64->32 (512 blocks). launch_bounds(256,4) caps VGPR at 128.

typedef _Float16 f16;
typedef _Float16 f16x8 __attribute__((ext_vector_type(8)));
typedef float    f32x4 __attribute__((ext_vector_type(4)));

__device__ __forceinline__ void async_cp16(const void* g, void* l) {
  __builtin_amdgcn_global_load_lds((const __attribute__((address_space(1))) void*)g,
                                   (__attribute__((address_space(3))) void*)l, 16, 0, 0);
}

__device__ __forceinline__ f16x8 splat8(f16 v) {
  f16x8 r;
#pragma unroll
  for (int e = 0; e < 8; ++e) r[e] = v;
  return r;
}

// ---------------------------------------------------------------------------
// GEMM: C[M,N] = act(A' * BT[N,K]^T + bias)
// AMODE: 1 = A fp32 [M,K], cvt->fp16 during staging (proj)
//        2 = A fp16 [M,K], tridiag band mix during staging (GCN)
// ---------------------------------------------------------------------------
template<int BM, int BN, int WAVES_M, int WAVES_N, bool RELU, bool HAS_BIAS, int AMODE>
__global__ __launch_bounds__(256, 4) void gemm_f16_kernel(
    const void* __restrict__ Aptr, const f16* __restrict__ BT,
    f16* __restrict__ C, const float* __restrict__ bias,
    int M, int N, int K)
{
  constexpr int BK = 64;
  constexpr int WM = BM / WAVES_M;
  constexpr int WN = BN / WAVES_N;
  constexpr int TM = WM / 16;
  constexpr int TN = WN / 16;
  constexpr int ITER_A = (BM * BK) / (256 * 8);
  constexpr int ITER_B = (BN * BK) / (256 * 8);
  constexpr int S = 2048;

  __shared__ __align__(16) f16 sA[BM * BK];
  __shared__ __align__(16) f16 sB[BN * BK];

  const int tid  = threadIdx.x;
  const int lane = tid & 63;
  const int wave = tid >> 6;
  const int wm   = wave / WAVES_N;
  const int wn   = wave % WAVES_N;
  const int m0   = blockIdx.x * BM;
  const int n0   = blockIdx.y * BN;

  uint32_t offA[ITER_A][3];
  f16      cfA[ITER_A][3];
  const float dM = 0.57735026919f;   // (3+1e-8)^-1/2
  const float dE = 0.70710678118f;   // (2+1e-8)^-1/2
#pragma unroll
  for (int j = 0; j < ITER_A; ++j) {
    const int linear = j * 256 + tid;
    const int row = linear >> 3;
    const int q   = (linear & 7) ^ (row & 7);
    const int gm  = m0 + row;
    if constexpr (AMODE == 1) {
      offA[j][0] = (uint32_t)(((size_t)gm * K + q * 8) * 4);
    } else {
      const int s = gm & (S - 1);
      const float dsv = (s == 0 || s == S - 1) ? dE : dM;
      const float cpf = (s > 0)     ? dsv * ((s - 1 == 0) ? dE : dM)     : 0.0f;
      const float csf = dsv * dsv;
      const float cnf = (s < S - 1) ? dsv * ((s + 1 == S - 1) ? dE : dM) : 0.0f;
      const int rm1 = (s > 0)     ? gm - 1 : gm;
      const int rp1 = (s < S - 1) ? gm + 1 : gm;
      offA[j][0] = (uint32_t)(((size_t)rm1 * K + q * 8) * 2);
      offA[j][1] = (uint32_t)(((size_t)gm  * K + q * 8) * 2);
      offA[j][2] = (uint32_t)(((size_t)rp1 * K + q * 8) * 2);
      cfA[j][0] = (f16)cpf; cfA[j][1] = (f16)csf; cfA[j][2] = (f16)cnf;
    }
  }

  f32x4 acc[TM][TN];
#pragma unroll
  for (int i = 0; i < TM; ++i)
#pragma unroll
    for (int j = 0; j < TN; ++j)
      acc[i][j] = (f32x4){0.f, 0.f, 0.f, 0.f};

  const int quad = lane >> 4;
  const int l16  = lane & 15;

  for (int kt = 0; kt < K; kt += BK) {
    __syncthreads();
    if constexpr (AMODE == 1) {
      const char* base = (const char*)Aptr + (size_t)kt * 4;
#pragma unroll
      for (int j = 0; j < ITER_A; ++j) {
        const float4* p = (const float4*)(base + offA[j][0]);
        const float4 a = p[0], b = p[1];
        f16x8 o;
        o[0] = (f16)a.x;  o[1] = (f16)a.y;  o[2] = (f16)a.z;  o[3] = (f16)a.w;
        o[4] = (f16)b.x;  o[5] = (f16)b.y;  o[6] = (f16)b.z;  o[7] = (f16)b.w;
        *(f16x8*)&sA[(size_t)(j * 256 + tid) * 8] = o;
      }
    } else {
      const char* base = (const char*)Aptr + (size_t)kt * 2;
#pragma unroll
      for (int j = 0; j < ITER_A; ++j) {
        f16x8 pv = *(const f16x8*)(base + offA[j][0]);
        f16x8 sv = *(const f16x8*)(base + offA[j][1]);
        f16x8 nv = *(const f16x8*)(base + offA[j][2]);
        f16x8 r = pv * splat8(cfA[j][0]);
        r += sv * splat8(cfA[j][1]);
        r += nv * splat8(cfA[j][2]);
        *(f16x8*)&sA[(size_t)(j * 256 + tid) * 8] = r;
      }
    }
#pragma unroll
    for (int j = 0; j < ITER_B; ++j) {
      const int linear = j * 256 + tid;
      const int row = linear >> 3;
      const int q   = (linear & 7) ^ (row & 7);
      async_cp16(BT + (size_t)(n0 + row) * K + kt + q * 8, &sB[linear * 8]);
    }
    __syncthreads();

#pragma unroll
    for (int kk = 0; kk < 2; ++kk) {
      const int c = quad + kk * 4;
      f16x8 af[TM], bf[TN];
#pragma unroll
      for (int mi = 0; mi < TM; ++mi) {
        const int ml = wm * WM + mi * 16 + l16;
        af[mi] = *(const f16x8*)&sA[ml * 64 + ((c ^ (ml & 7)) * 8)];
      }
#pragma unroll
      for (int ni = 0; ni < TN; ++ni) {
        const int nl = wn * WN + ni * 16 + l16;
        bf[ni] = *(const f16x8*)&sB[nl * 64 + ((c ^ (nl & 7)) * 8)];
      }
#pragma unroll
      for (int mi = 0; mi < TM; ++mi)
#pragma unroll
        for (int ni = 0; ni < TN; ++ni)
          acc[mi][ni] = __builtin_amdgcn_mfma_f32_16x16x32_f16(
              af[mi], bf[ni], acc[mi][ni], 0, 0, 0);
    }
  }

#pragma unroll
  for (int ni = 0; ni < TN; ++ni) {
    const int nc = n0 + wn * WN + ni * 16 + l16;
    const float bv = HAS_BIAS ? bias[nc] : 0.0f;
#pragma unroll
    for (int mi = 0; mi < TM; ++mi) {
#pragma unroll
      for (int r = 0; r < 4; ++r) {
        const int mr = m0 + wm * WM + mi * 16 + quad * 4 + r;
        float v = acc[mi][ni][r] + bv;
        if (RELU) v = fmaxf(v, 0.0f);
        C[(size_t)mr * N + nc] = (f16)v;
      }
    }
  }
}

// ---------------------------------------------------------------------------
// Fused head, 32 rows/block (512 blocks): z1[32][256] LDS -> z2[32][128] LDS
// -> sigmoid dot. Phase1: sA(4K)+sB(32K); Phase2 reuses: z2s(8.5K)+sB2(16K);
// zs(16.9K) persistent at 36864. Total ~53.8KB -> 2 blocks/CU.
// ---------------------------------------------------------------------------
__global__ __launch_bounds__(256) void head_fused_kernel(
    const f16* __restrict__ h, const f16* __restrict__ S1T,
    const f16* __restrict__ S2T,
    const float* __restrict__ s1b, const float* __restrict__ s2b,
    const float* __restrict__ s3w, const float* __restrict__ s3b,
    float* __restrict__ out)
{
  __shared__ __align__(16) char smem[36864 + 32 * 264 * 2];
  f16* sA  = (f16*)smem;             // [32*64]   = 4KB
  f16* sB  = (f16*)(smem + 4096);    // [256*64]  = 32KB
  f16* zs  = (f16*)(smem + 36864);   // [32][264]
  f16* z2s = (f16*)smem;             // [32][136] = 8.5KB (reuses sA+sB head)
  f16* sB2 = (f16*)(smem + 8704);    // [128*64]  = 16KB

  const int tid  = threadIdx.x;
  const int lane = tid & 63;
  const int wave = tid >> 6;
  const int quad = lane >> 4;
  const int l16  = lane & 15;
  const int m0   = blockIdx.x * 32;

  // ---- GEMM1: z1[32][256] = relu(h[32x512] @ S1T^T + s1b); wave = 32x64 ----
  f32x4 acc[2][4];
#pragma unroll
  for (int i = 0; i < 2; ++i)
#pragma unroll
    for (int j = 0; j < 4; ++j) acc[i][j] = (f32x4){0.f, 0.f, 0.f, 0.f};

  for (int kt = 0; kt < 512; kt += 64) {
    __syncthreads();
    {   // A: 32x64 halfs = 256 chunks, 1 iter
      const int linear = tid;
      const int row = linear >> 3;
      const int q   = (linear & 7) ^ (row & 7);
      async_cp16(h + (size_t)(m0 + row) * 512 + kt + q * 8, &sA[linear * 8]);
    }
#pragma unroll
    for (int j = 0; j < 8; ++j) {   // B: 256x64 halfs = 2048 chunks
      const int linear = j * 256 + tid;
      const int row = linear >> 3;
      const int q   = (linear & 7) ^ (row & 7);
      async_cp16(S1T + (size_t)row * 512 + kt + q * 8, &sB[linear * 8]);
    }
    __syncthreads();
#pragma unroll
    for (int kk = 0; kk < 2; ++kk) {
      const int c = quad + kk * 4;
      f16x8 af[2], bf[4];
#pragma unroll
      for (int mi = 0; mi < 2; ++mi) {
        const int ml = mi * 16 + l16;
        af[mi] = *(const f16x8*)&sA[ml * 64 + ((c ^ (ml & 7)) * 8)];
      }
#pragma unroll
      for (int ni = 0; ni < 4; ++ni) {
        const int nl = wave * 64 + ni * 16 + l16;
        bf[ni] = *(const f16x8*)&sB[nl * 64 + ((c ^ (nl & 7)) * 8)];
      }
#pragma unroll
      for (int mi = 0; mi < 2; ++mi)
#pragma unroll
        for (int ni = 0; ni < 4; ++ni)
          acc[mi][ni] = __builtin_amdgcn_mfma_f32_16x16x32_f16(
              af[mi], bf[ni], acc[mi][ni], 0, 0, 0);
    }
  }
#pragma unroll
  for (int ni = 0; ni < 4; ++ni) {
    const int nc = wave * 64 + ni * 16 + l16;
    const float bv = s1b[nc];
#pragma unroll
    for (int mi = 0; mi < 2; ++mi)
#pragma unroll
      for (int r = 0; r < 4; ++r) {
        const int row = mi * 16 + quad * 4 + r;
        zs[row * 264 + nc] = (f16)fmaxf(acc[mi][ni][r] + bv, 0.0f);
      }
  }
  __syncthreads();

  // ---- GEMM2: z2[32][128] = relu(z1 @ S2T^T + s2b); wave = 32x32 ----
  f32x4 acc2[2][2];
#pragma unroll
  for (int i = 0; i < 2; ++i)
#pragma unroll
    for (int j = 0; j < 2; ++j) acc2[i][j] = (f32x4){0.f, 0.f, 0.f, 0.f};

  for (int kt2 = 0; kt2 < 4; ++kt2) {
    __syncthreads();
#pragma unroll
    for (int j = 0; j < 4; ++j) {   // B2: 128x64 halfs = 1024 chunks
      const int linear = j * 256 + tid;
      const int row = linear >> 3;
      const int q   = (linear & 7) ^ (row & 7);
      async_cp16(S2T + (size_t)row * 256 + kt2 * 64 + q * 8, &sB2[linear * 8]);
    }
    __syncthreads();
#pragma unroll
    for (int kk = 0; kk < 2; ++kk) {
      const int c = quad + kk * 4;
      f16x8 af[2], bf[2];
#pragma unroll
      for (int mi = 0; mi < 2; ++mi) {
        const int row = mi * 16 + l16;
        af[mi] = *(const f16x8*)&zs[row * 264 + (kt2 * 8 + c) * 8];
      }
#pragma unroll
      for (int ni = 0; ni < 2; ++ni) {
        const int nl = wave * 32 + ni * 16 + l16;
        bf[ni] = *(const f16x8*)&sB2[nl * 64 + ((c ^ (nl & 7)) * 8)];
      }
#pragma unroll
      for (int mi = 0; mi < 2; ++mi)
#pragma unroll
        for (int ni = 0; ni < 2; ++ni)
          acc2[mi][ni] = __builtin_amdgcn_mfma_f32_16x16x32_f16(
              af[mi], bf[ni], acc2[mi][ni], 0, 0, 0);
    }
  }
  __syncthreads();
#pragma unroll
  for (int ni = 0; ni < 2; ++ni) {
    const int nc = wave * 32 + ni * 16 + l16;
    const float bv = s2b[nc];
#pragma unroll
    for (int mi = 0; mi < 2; ++mi)
#pragma unroll
      for (int r = 0; r < 4; ++r) {
        const int row = mi * 16 + quad * 4 + r;
        z2s[row * 136 + nc] = (f16)fmaxf(acc2[mi][ni][r] + bv, 0.0f);
      }
  }
  __syncthreads();

  // ---- out[m] = sigmoid(dot(z2[m,:128], w) + b), 8 threads/row ----
  const int m  = tid >> 3;
  const int qd = tid & 7;
  float p = 0.f;
#pragma unroll
  for (int j = 0; j < 2; ++j) {
    f16x8 v = *(const f16x8*)&z2s[m * 136 + qd * 16 + j * 8];
#pragma unroll
    for (int e = 0; e < 8; ++e) p += (float)v[e] * s3w[qd * 16 + j * 8 + e];
  }
  p += __shfl_xor(p, 1);
  p += __shfl_xor(p, 2);
  p += __shfl_xor(p, 4);
  if (qd == 0) out[m0 + m] = 1.0f / (1.0f + expf(-(p + s3b[0])));
}

// ---------------------------------------------------------------------------
// Prep: 64x64 LDS tile-transposes of all weights (coalesced both sides).
// ---------------------------------------------------------------------------
__global__ __launch_bounds__(256) void prep_kernel(
    const float* __restrict__ Wp, f16* __restrict__ WpT,
    const float* __restrict__ gW, f16* __restrict__ GT,
    const float* __restrict__ s1W, f16* __restrict__ S1T,
    const float* __restrict__ s2W, f16* __restrict__ S2T)
{
  __shared__ f16 s[64 * 68];
  const int tid = threadIdx.x;
  int b = blockIdx.x;

  const float* W; f16* WT; int K, N, tile;
  if (b < 128)      { W = Wp;  WT = WpT; K = 1024; N = 512; tile = b; }
  else if (b < 320) { const int i = (b - 128) >> 6;
                      W = gW + (size_t)i * 262144; WT = GT + (size_t)i * 262144;
                      K = 512; N = 512; tile = (b - 128) & 63; }
  else if (b < 352) { W = s1W; WT = S1T; K = 512; N = 256; tile = b - 320; }
  else              { W = s2W; WT = S2T; K = 256; N = 128; tile = b - 352; }

  const int nt = tile % (N >> 6);
  const int kt = tile / (N >> 6);
#pragma unroll
  for (int it = 0; it < 16; ++it) {
    const int i  = it * 256 + tid;
    const int rk = i >> 6, rn = i & 63;
    s[rn * 68 + rk] = (f16)W[(size_t)(kt * 64 + rk) * N + nt * 64 + rn];
  }
  __syncthreads();
#pragma unroll
  for (int it = 0; it < 16; ++it) {
    const int i  = it * 256 + tid;
    const int rn = i >> 6, rk = i & 63;
    WT[(size_t)(nt * 64 + rn) * K + kt * 64 + rk] = s[rn * 68 + rk];
  }
}

// ---------------------------------------------------------------------------
extern "C" void kernel_launch(void* const* d_in, const int* in_sizes, int n_in,
                              void* d_out, int out_size, void* d_ws, size_t ws_size,
                              hipStream_t stream) {
  (void)in_sizes; (void)n_in; (void)out_size; (void)ws_size;
  const float* x   = (const float*)d_in[0];
  const float* Wp  = (const float*)d_in[1];
  const float* bp  = (const float*)d_in[2];
  const float* gW  = (const float*)d_in[3];
  const float* gb  = (const float*)d_in[4];
  const float* s1W = (const float*)d_in[5];
  const float* s1b = (const float*)d_in[6];
  const float* s2W = (const float*)d_in[7];
  const float* s2b = (const float*)d_in[8];
  const float* s3W = (const float*)d_in[9];
  const float* s3b = (const float*)d_in[10];
  float* out = (float*)d_out;

  constexpr int M = 16384;
  char* ws = (char*)d_ws;
  f16* hA  = (f16*)(ws + 0);            // 16384x512
  f16* hB  = (f16*)(ws + 16777216);     // 16384x512
  f16* WpT = (f16*)(ws + 33554432);     // [512,1024]
  f16* GT  = (f16*)(ws + 34603008);     // 3x[512,512]
  f16* S1T = (f16*)(ws + 36175872);     // [256,512]
  f16* S2T = (f16*)(ws + 36438016);     // [128,256]

  prep_kernel<<<360, 256, 0, stream>>>(Wp, WpT, gW, GT, s1W, S1T, s2W, S2T);

  // proj: hA = x @ Wp + bp  (fp32->fp16 cvt fused in A-staging)
  gemm_f16_kernel<64, 128, 2, 2, false, true, 1>
      <<<dim3(M / 64, 4), 256, 0, stream>>>(x, WpT, hA, bp, M, 512, 1024);

  // GCN layers: h' = (adj @ h) @ W + b  (band mix fused in A-staging)
  gemm_f16_kernel<64, 128, 2, 2, true, true, 2>
      <<<dim3(M / 64, 4), 256, 0, stream>>>(hA, GT, hB, gb, M, 512, 512);
  gemm_f16_kernel<64, 128, 2, 2, true, true, 2>
      <<<dim3(M / 64, 4), 256, 0, stream>>>(hB, GT + 262144, hA, gb + 512, M, 512, 512);
  gemm_f16_kernel<64, 128, 2, 2, false, true, 2>
      <<<dim3(M / 64, 4), 256, 0, stream>>>(hA, GT + 524288, hB, gb + 1024, M, 512, 512);

  head_fused_kernel<<<M / 32, 256, 0, stream>>>(hB, S1T, S2T, s1b, s2b, s3W, s3b, out);
}